// Round 2
// baseline (310.627 us; speedup 1.0000x reference)
//
#include <hip/hip_runtime.h>
#include <hip/hip_bf16.h>

// Problem: B=2, T=8192, C=64, retention attention with causal decay gamma=0.96875,
// GroupNorm(8 groups, eps=1e-6), output stored transposed (B,C,T)-flat.
// All inputs/outputs are float32 (per reference). gamma^1024 ~ 7.6e-15 ->
// sliding window of NCH*64 suffices (truncation << 2% threshold).

constexpr int BATCH = 2;
constexpr int SEQ   = 8192;
constexpr int CH    = 64;
constexpr int NCH   = 17;          // chunks of 64: current + 16 back (window 1024..1087)
constexpr float LOG2G = -0.045803690f;  // log2(0.96875)

// ---------------------------------------------------------------------------
// Kernel 1: Q/K/V = Qin @ {Wq,Wk,Wv}; fp32 outputs to workspace.
// One block per 64 rows. W (3x64x64) + X tile (64x64) staged in LDS.
// ---------------------------------------------------------------------------
__global__ __launch_bounds__(256) void qkv_kernel(
    const float* __restrict__ Xin,
    const float* __restrict__ Wq,
    const float* __restrict__ Wk,
    const float* __restrict__ Wv,
    float* __restrict__ Qf, float* __restrict__ Kf, float* __restrict__ Vf)
{
    __shared__ float sW[3][64][64];
    __shared__ float sX[64][65];
    const int tid = threadIdx.x;
    const size_t row0 = (size_t)blockIdx.x * 64;

    for (int i = tid; i < 3 * 64 * 64; i += 256) {
        int m = i >> 12, rc = i & 4095;
        const float* W = (m == 0) ? Wq : ((m == 1) ? Wk : Wv);
        sW[m][rc >> 6][rc & 63] = W[rc];
    }
    for (int i = tid; i < 64 * 64; i += 256)
        sX[i >> 6][i & 63] = Xin[row0 * 64 + i];
    __syncthreads();

    for (int o = tid; o < 3 * 64 * 64; o += 256) {
        int m = o >> 12, rc = o & 4095;
        int r = rc >> 6, c = rc & 63;
        float acc = 0.f;
        #pragma unroll 16
        for (int k = 0; k < 64; k++)
            acc += sX[r][k] * sW[m][k][c];   // sX broadcast per wave; sW 2-way (free)
        float* O = (m == 0) ? Qf : ((m == 1) ? Kf : Vf);
        O[(row0 + r) * CH + c] = acc;
    }
}

// ---------------------------------------------------------------------------
// Kernel 2: sliding-window retention.
// Block = one 64-row Q tile (grid 256). Loop NCH K/V chunks through LDS:
//   S[r][s] = (q_r . k_s) * gamma^(t-s)  (0 if t<s), then acc += S @ Vchunk.
// Thread owns (r = tid&63, 16 channels cg..cg+15).
// ---------------------------------------------------------------------------
__global__ __launch_bounds__(256) void attn_kernel(
    const float* __restrict__ Qf, const float* __restrict__ Kf,
    const float* __restrict__ Vf, float* __restrict__ Of)
{
    __shared__ float sQ[64][65];
    __shared__ float sK[64][65];
    __shared__ float sV[64][65];
    __shared__ float sS[64][65];
    __shared__ float gtab[NCH * 64 + 64];

    const int tid  = threadIdx.x;
    const int tile = blockIdx.x;
    const int b    = tile >> 7;            // / (SEQ/64)=128
    const int t0   = (tile & 127) << 6;
    const float* Qb = Qf + (size_t)b * SEQ * CH;
    const float* Kb = Kf + (size_t)b * SEQ * CH;
    const float* Vb = Vf + (size_t)b * SEQ * CH;

    for (int i = tid; i < 64 * 64; i += 256)
        sQ[i >> 6][i & 63] = Qb[(size_t)(t0 + (i >> 6)) * CH + (i & 63)];
    for (int d = tid; d < NCH * 64 + 64; d += 256)
        gtab[d] = exp2f((float)d * LOG2G);

    const int r  = tid & 63;
    const int cg = (tid >> 6) << 4;        // 0,16,32,48 per wave
    float acc[16];
    #pragma unroll
    for (int j = 0; j < 16; j++) acc[j] = 0.f;

    __syncthreads();

    for (int ci = 0; ci < NCH; ci++) {
        const int s0 = t0 - (NCH - 1 - ci) * 64;   // multiple of 64; <0 => whole chunk OOB
        if (s0 >= 0) {
            for (int i = tid; i < 64 * 64; i += 256) {
                int rr = i >> 6, c = i & 63;
                sK[rr][c] = Kb[(size_t)(s0 + rr) * CH + c];
                sV[rr][c] = Vb[(size_t)(s0 + rr) * CH + c];
            }
        }
        __syncthreads();
        if (s0 >= 0) {
            float sc[16];
            #pragma unroll
            for (int j = 0; j < 16; j++) sc[j] = 0.f;
            for (int k = 0; k < 64; k++) {
                float qv = sQ[r][k];               // lanes r-varying, stride 65 -> 2-way free
                #pragma unroll
                for (int j = 0; j < 16; j++)
                    sc[j] += qv * sK[cg + j][k];   // broadcast per wave
            }
            const int base = t0 - s0;
            #pragma unroll
            for (int j = 0; j < 16; j++) {
                int d = base + r - (cg + j);
                float w = (d >= 0) ? gtab[d] : 0.f;
                sS[r][cg + j] = sc[j] * w;
            }
        }
        __syncthreads();
        if (s0 >= 0) {
            for (int s = 0; s < 64; s++) {
                float sv = sS[r][s];               // 2-way free
                #pragma unroll
                for (int j = 0; j < 16; j++)
                    acc[j] += sv * sV[s][cg + j];  // broadcast per wave
            }
        }
        __syncthreads();
    }

    // stage through LDS for coalesced fp32 store
    #pragma unroll
    for (int j = 0; j < 16; j++) sS[r][cg + j] = acc[j];
    __syncthreads();
    for (int i = tid; i < 64 * 64; i += 256)
        Of[((size_t)(b * SEQ) + t0 + (i >> 6)) * CH + (i & 63)] = sS[i >> 6][i & 63];
}

// ---------------------------------------------------------------------------
// Kernel 3: GroupNorm (8 groups of 8, biased var, eps=1e-6, affine) +
// transposed fp32 store: d_out[(b*64 + c)*SEQ + t] = gn(out)[b,t,c].
// ---------------------------------------------------------------------------
__global__ __launch_bounds__(256) void gn_kernel(
    const float* __restrict__ Of,
    const float* __restrict__ gw, const float* __restrict__ gb,
    float* __restrict__ out)
{
    __shared__ float sX[64][65];
    __shared__ float sw[64];
    __shared__ float sb[64];
    const int tid  = threadIdx.x;
    const int tile = blockIdx.x;
    const int b    = tile >> 7;
    const int t0   = (tile & 127) << 6;

    for (int i = tid; i < 64 * 64; i += 256)
        sX[i >> 6][i & 63] = Of[((size_t)(b * SEQ) + t0) * CH + i];
    if (tid < 64) {
        sw[tid] = gw[tid];
        sb[tid] = gb[tid];
    }
    __syncthreads();

    for (int p = tid; p < 64 * 8; p += 256) {      // (row, group) pairs
        int rr = p >> 3, g = p & 7;
        float* x = &sX[rr][g * 8];
        float m = 0.f;
        #pragma unroll
        for (int i = 0; i < 8; i++) m += x[i];
        m *= 0.125f;
        float v = 0.f;
        #pragma unroll
        for (int i = 0; i < 8; i++) { float d = x[i] - m; v += d * d; }
        v *= 0.125f;
        float rs = rsqrtf(v + 1e-6f);
        #pragma unroll
        for (int i = 0; i < 8; i++) x[i] = (x[i] - m) * rs;
    }
    __syncthreads();

    for (int i = tid; i < 64 * 64; i += 256) {
        int c = i >> 6, t = i & 63;                // lanes t-contiguous -> coalesced
        float val = sX[t][c] * sw[c] + sb[c];
        out[((size_t)b * CH + c) * SEQ + t0 + t] = val;
    }
}

// ---------------------------------------------------------------------------
extern "C" void kernel_launch(void* const* d_in, const int* in_sizes, int n_in,
                              void* d_out, int out_size, void* d_ws, size_t ws_size,
                              hipStream_t stream)
{
    const float* Xin = (const float*)d_in[0];
    const float* Wq  = (const float*)d_in[1];
    const float* Wk  = (const float*)d_in[2];
    const float* Wv  = (const float*)d_in[3];
    const float* gw  = (const float*)d_in[4];
    const float* gb  = (const float*)d_in[5];

    const size_t NROW = (size_t)BATCH * SEQ;       // 16384
    float* Qf = (float*)d_ws;                      // 4.19 MB each
    float* Kf = Qf + NROW * CH;
    float* Vf = Kf + NROW * CH;
    float* Of = Vf + NROW * CH;                    // total 16.8 MB of ws

    qkv_kernel<<<dim3(NROW / 64), dim3(256), 0, stream>>>(Xin, Wq, Wk, Wv, Qf, Kf, Vf);
    attn_kernel<<<dim3(256), dim3(256), 0, stream>>>(Qf, Kf, Vf, Of);
    gn_kernel<<<dim3(256), dim3(256), 0, stream>>>(Of, gw, gb, (float*)d_out);
}

// Round 4
// 117.634 us; speedup vs baseline: 2.6406x; 2.6406x over previous
//
#include <hip/hip_runtime.h>

// B=2, T=8192, C=64 retention attention, gamma=0.96875, GroupNorm(8), output (B,C,T)-flat.
// fp32 in/out. Sliding window NCH*64 (gamma^1024 ~ 7.6e-15, << 2% threshold).
// R4: fp16 MFMA (16x16x32) — bf16's 2^-8 eps gave 2.3% error (threshold 2.0%);
// fp16's 2^-11 predicts ~0.3%. Ranges (|Q|,|K|,|S|,|V| < ~2) safe in fp16.

constexpr int BATCH = 2;
constexpr int SEQ   = 8192;
constexpr int CH    = 64;
constexpr int NCH   = 17;
constexpr float LOG2G = -0.045803690f;  // log2(0.96875)

typedef __attribute__((ext_vector_type(8))) _Float16       half8;    // 8 fp16 (4 VGPRs)
typedef __attribute__((ext_vector_type(8))) unsigned short ushort8;
typedef __attribute__((ext_vector_type(4))) float          f32x4;

__device__ inline unsigned short f2h(float x) {           // RNE float->fp16 bits
    _Float16 h = (_Float16)x;
    return __builtin_bit_cast(unsigned short, h);
}

// ---------------------------------------------------------------------------
// Kernel 1: QKV projection (scalar fp32 math) ->
//   Qh[t][c] fp16, Kh[t][c] fp16, Vt[c][t] fp16 (transpose staged via LDS).
// ---------------------------------------------------------------------------
__global__ __launch_bounds__(256) void qkv_kernel(
    const float* __restrict__ Xin,
    const float* __restrict__ Wq, const float* __restrict__ Wk, const float* __restrict__ Wv,
    unsigned short* __restrict__ Qh, unsigned short* __restrict__ Kh,
    unsigned short* __restrict__ Vt)
{
    __shared__ float sW[3][64][64];
    __shared__ float sX[64][65];
    __shared__ unsigned short sVt[64][65];
    const int tid = threadIdx.x;
    const size_t row0 = (size_t)blockIdx.x * 64;
    const int b  = (int)(row0 >> 13);
    const int t0 = (int)(row0 & (SEQ - 1));

    for (int i = tid; i < 3 * 64 * 64; i += 256) {
        int m = i >> 12, rc = i & 4095;
        const float* W = (m == 0) ? Wq : ((m == 1) ? Wk : Wv);
        sW[m][rc >> 6][rc & 63] = W[rc];
    }
    for (int i = tid; i < 64 * 64; i += 256)
        sX[i >> 6][i & 63] = Xin[row0 * 64 + i];
    __syncthreads();

    for (int o = tid; o < 3 * 64 * 64; o += 256) {
        int m = o >> 12, rc = o & 4095;
        int r = rc >> 6, c = rc & 63;
        float acc = 0.f;
        #pragma unroll 16
        for (int k = 0; k < 64; k++)
            acc += sX[r][k] * sW[m][k][c];
        unsigned short hv = f2h(acc);
        if (m == 0)      Qh[(row0 + r) * CH + c] = hv;
        else if (m == 1) Kh[(row0 + r) * CH + c] = hv;
        else             sVt[c][r] = hv;          // transpose in LDS
    }
    __syncthreads();
    for (int i = tid; i < 64 * 64; i += 256) {
        int c = i >> 6, r = i & 63;               // coalesced over r
        Vt[((size_t)(b * CH + c)) * SEQ + t0 + r] = sVt[c][r];
    }
}

// ---------------------------------------------------------------------------
// Kernel 2: MFMA retention + fused GroupNorm + transposed store.
// Grid 256 (one 64-row tile each), block 512 = 8 waves.
// Wave w: strip = w>>1 (16 t-rows), ch = w&1 (32 s/c-cols half).
// mfma_f32_16x16x32_f16 layouts (dtype-independent, m89/m121/m124):
//   A: m=lane&15, k=(lane>>4)*8+j   B: n=lane&15, k=(lane>>4)*8+j
//   C/D: col=lane&15, row=(lane>>4)*4+reg
// ---------------------------------------------------------------------------
__global__ __launch_bounds__(512) void attn_kernel(
    const unsigned short* __restrict__ Qh, const unsigned short* __restrict__ Kh,
    const unsigned short* __restrict__ Vt,
    const float* __restrict__ gnw, const float* __restrict__ gnb,
    float* __restrict__ out)
{
    __shared__ unsigned short sK [64][88];   // stride 88: rows 176B (16B-aligned), <=2-way banks
    __shared__ unsigned short sVc[64][88];   // sVc[c][s]
    __shared__ unsigned short sS [64][88];   // S roundtrip, fp16
    __shared__ float sO[64][65];
    __shared__ float swv[64], sbv[64];

    const int tid  = threadIdx.x;
    const int b    = blockIdx.x >> 7;
    const int t0   = (blockIdx.x & 127) << 6;
    const int lane = tid & 63;
    const int w    = tid >> 6;
    const int strip = w >> 1, ch = w & 1;
    const int l15 = lane & 15, q4 = lane >> 4;
    const int wrow0 = strip << 4;

    if (tid < 64) { swv[tid] = gnw[tid]; sbv[tid] = gnb[tid]; }

    // Q A-fragments: registers for the whole tile (global 16B loads)
    const unsigned short* Qp = Qh + ((size_t)(b * SEQ + t0 + wrow0 + l15)) * CH + q4 * 8;
    const half8 qf0 = *(const half8*)Qp;
    const half8 qf1 = *(const half8*)(Qp + 32);

    // per-lane gamma^(row-col) table (chunk-independent part of the decay)
    float wrc[2][4];
    #pragma unroll
    for (int cti = 0; cti < 2; ++cti) {
        int cl = (ch * 2 + cti) * 16 + l15;
        #pragma unroll
        for (int i = 0; i < 4; ++i)
            wrc[cti][i] = exp2f((float)(wrow0 + q4 * 4 + i - cl) * LOG2G);
    }

    f32x4 acc0 = {0.f, 0.f, 0.f, 0.f};
    f32x4 acc1 = {0.f, 0.f, 0.f, 0.f};

    for (int ci = 0; ci < NCH; ++ci) {
        const int d16  = (NCH - 1) - ci;
        const int s0   = t0 - d16 * 64;
        const int base = d16 * 64;

        if (s0 >= 0) {                                    // stage K and V^T chunks
            const int s   = tid >> 3;                     // also 'c' for Vt
            const int off = (tid & 7) * 8;
            ushort8 kv = *(const ushort8*)(Kh + ((size_t)(b * SEQ + s0 + s)) * CH + off);
            *(ushort8*)&sK[s][off] = kv;
            ushort8 vv = *(const ushort8*)(Vt + ((size_t)(b * CH + s)) * SEQ + s0 + off);
            *(ushort8*)&sVc[s][off] = vv;
        }
        __syncthreads();

        if (s0 >= 0) {                                    // S = (Q K^T) * decay -> sS (fp16)
            const float gbase = exp2f((float)base * LOG2G);
            #pragma unroll
            for (int cti = 0; cti < 2; ++cti) {
                const int ct = ch * 2 + cti;
                const unsigned short* kp = &sK[ct * 16 + l15][q4 * 8];
                half8 kf0 = *(const half8*)kp;
                half8 kf1 = *(const half8*)(kp + 32);
                f32x4 s = {0.f, 0.f, 0.f, 0.f};
                s = __builtin_amdgcn_mfma_f32_16x16x32_f16(qf0, kf0, s, 0, 0, 0);
                s = __builtin_amdgcn_mfma_f32_16x16x32_f16(qf1, kf1, s, 0, 0, 0);
                const int cl = ct * 16 + l15;
                #pragma unroll
                for (int i = 0; i < 4; ++i) {
                    const int rl = wrow0 + q4 * 4 + i;
                    const float wv = (base + rl - cl >= 0) ? gbase * wrc[cti][i] : 0.f;
                    sS[rl][cl] = f2h(s[i] * wv);
                }
            }
        }
        __syncthreads();

        if (s0 >= 0) {                                    // O += S @ V
            const unsigned short* sp = &sS[wrow0 + l15][q4 * 8];
            half8 af0 = *(const half8*)sp;
            half8 af1 = *(const half8*)(sp + 32);
            {
                const unsigned short* vp = &sVc[(ch * 2) * 16 + l15][q4 * 8];
                half8 vf0 = *(const half8*)vp;
                half8 vf1 = *(const half8*)(vp + 32);
                acc0 = __builtin_amdgcn_mfma_f32_16x16x32_f16(af0, vf0, acc0, 0, 0, 0);
                acc0 = __builtin_amdgcn_mfma_f32_16x16x32_f16(af1, vf1, acc0, 0, 0, 0);
            }
            {
                const unsigned short* vp = &sVc[(ch * 2 + 1) * 16 + l15][q4 * 8];
                half8 vf0 = *(const half8*)vp;
                half8 vf1 = *(const half8*)(vp + 32);
                acc1 = __builtin_amdgcn_mfma_f32_16x16x32_f16(af0, vf0, acc1, 0, 0, 0);
                acc1 = __builtin_amdgcn_mfma_f32_16x16x32_f16(af1, vf1, acc1, 0, 0, 0);
            }
        }
        __syncthreads();                                  // before next staging overwrites sK/sVc
    }

    // ---- epilogue: GroupNorm(8 groups of 8) + transposed store ----
    #pragma unroll
    for (int i = 0; i < 4; ++i) {
        sO[wrow0 + q4 * 4 + i][(ch * 2) * 16 + l15]     = acc0[i];
        sO[wrow0 + q4 * 4 + i][(ch * 2 + 1) * 16 + l15] = acc1[i];
    }
    __syncthreads();
    {
        const int r = tid >> 3, g = tid & 7;              // 512 = 64 rows x 8 groups
        float* x = &sO[r][g * 8];
        float m = 0.f;
        #pragma unroll
        for (int i = 0; i < 8; ++i) m += x[i];
        m *= 0.125f;
        float v = 0.f;
        #pragma unroll
        for (int i = 0; i < 8; ++i) { float d = x[i] - m; v += d * d; }
        v *= 0.125f;
        const float rs = rsqrtf(v + 1e-6f);
        #pragma unroll
        for (int i = 0; i < 8; ++i) x[i] = (x[i] - m) * rs;
    }
    __syncthreads();
    for (int i = tid; i < 64 * 64; i += 512) {
        const int c = i >> 6, t = i & 63;                 // coalesced over t
        out[((size_t)(b * CH + c)) * SEQ + t0 + t] = sO[t][c] * swv[c] + sbv[c];
    }
}

// ---------------------------------------------------------------------------
extern "C" void kernel_launch(void* const* d_in, const int* in_sizes, int n_in,
                              void* d_out, int out_size, void* d_ws, size_t ws_size,
                              hipStream_t stream)
{
    const float* Xin = (const float*)d_in[0];
    const float* Wq  = (const float*)d_in[1];
    const float* Wk  = (const float*)d_in[2];
    const float* Wv  = (const float*)d_in[3];
    const float* gnw = (const float*)d_in[4];
    const float* gnb = (const float*)d_in[5];

    const size_t NROW = (size_t)BATCH * SEQ;             // 16384
    unsigned short* Qh = (unsigned short*)d_ws;          // 2 MB each (fp16)
    unsigned short* Kh = Qh + NROW * CH;
    unsigned short* Vt = Kh + NROW * CH;

    qkv_kernel<<<dim3(NROW / 64), dim3(256), 0, stream>>>(Xin, Wq, Wk, Wv, Qh, Kh, Vt);
    attn_kernel<<<dim3(256), dim3(512), 0, stream>>>(Qh, Kh, Vt, gnw, gnb, (float*)d_out);
}

// Round 5
// 102.762 us; speedup vs baseline: 3.0228x; 1.1447x over previous
//
#include <hip/hip_runtime.h>

// B=2, T=8192, C=64 retention attention, gamma=0.96875, GroupNorm(8), output (B,C,T)-flat.
// fp32 in/out. Sliding window of 17 64-wide s-chunks (gamma^1024 ~ 7.6e-15 << 2% threshold).
// R5: barrier-free per-wave attn (16-row tiles, S^T operand swap -> wave-private LDS
// roundtrip, K/V direct from L2 with register double-buffer prefetch, fused GN);
// qkv MFMA-ized. mfma_f32_16x16x32_f16 layouts (R4-validated):
//   A: m=lane&15, k=(lane>>4)*8+j   B: n=lane&15, k=(lane>>4)*8+j
//   C/D: col(n)=lane&15, row(m)=(lane>>4)*4+reg

constexpr int SEQ = 8192;
constexpr int CH  = 64;
constexpr float LOG2G = -0.045803690f;   // log2(0.96875)

typedef __attribute__((ext_vector_type(8))) _Float16 half8;
typedef __attribute__((ext_vector_type(4))) float    f32x4;

__device__ inline unsigned short f2h(float x) {
    _Float16 h = (_Float16)x;
    return __builtin_bit_cast(unsigned short, h);
}

// ---------------------------------------------------------------------------
// Kernel 1: QKV projection via MFMA. Grid 256 (64-row tiles), block 256 (4 waves).
// sWt[m][c][k] = W_m[k][c] fp16 (stride 72 u16 keeps b128 reads ~conflict-free).
// Q,K: D = mfma(X, Wt) -> Q[t][c]. V^T: D = mfma(Wt_v, X) -> Vt[c][t] directly.
// ---------------------------------------------------------------------------
__global__ __launch_bounds__(256) void qkv_kernel(
    const float* __restrict__ Xin, const float* __restrict__ Wq,
    const float* __restrict__ Wk, const float* __restrict__ Wv,
    unsigned short* __restrict__ Qh, unsigned short* __restrict__ Kh,
    unsigned short* __restrict__ Vt)
{
    __shared__ unsigned short sWt[3][64][72];
    const int tid = threadIdx.x;
    const size_t row0 = (size_t)blockIdx.x * 64;
    const int b  = (int)(row0 >> 13);
    const int t0 = (int)(row0 & (SEQ - 1));

    {   // stage W^T fp16: thread reads W[k][c],W[k+1][c] (coalesced rows), packs b32
        const int c  = tid & 63;
        const int k0 = (tid >> 6) * 2;
        #pragma unroll
        for (int m = 0; m < 3; ++m) {
            const float* W = (m == 0) ? Wq : ((m == 1) ? Wk : Wv);
            #pragma unroll
            for (int it = 0; it < 8; ++it) {
                const int k = k0 + it * 8;
                const unsigned lo = f2h(W[k * 64 + c]);
                const unsigned hi = f2h(W[(k + 1) * 64 + c]);
                *(unsigned int*)&sWt[m][c][k] = lo | (hi << 16);
            }
        }
    }

    const int l15 = tid & 15, q4 = (tid >> 4) & 3, wvi = tid >> 6;

    half8 xf[2];                                  // X A/B-fragments (fp32 -> fp16)
    {
        const float* Xp = Xin + (row0 + (size_t)(wvi * 16 + l15)) * 64;
        #pragma unroll
        for (int h = 0; h < 2; ++h) {
            const f32x4 a  = *(const f32x4*)(Xp + h * 32 + q4 * 8);
            const f32x4 bb = *(const f32x4*)(Xp + h * 32 + q4 * 8 + 4);
            half8 t;
            t[0] = (_Float16)a[0];  t[1] = (_Float16)a[1];
            t[2] = (_Float16)a[2];  t[3] = (_Float16)a[3];
            t[4] = (_Float16)bb[0]; t[5] = (_Float16)bb[1];
            t[6] = (_Float16)bb[2]; t[7] = (_Float16)bb[3];
            xf[h] = t;
        }
    }
    __syncthreads();

    const int trow = (int)row0 + wvi * 16;
    #pragma unroll
    for (int m = 0; m < 2; ++m) {                 // Q then K: D rows=t, cols=c
        unsigned short* O = (m == 0) ? Qh : Kh;
        #pragma unroll
        for (int ct = 0; ct < 4; ++ct) {
            const half8 wf0 = *(const half8*)&sWt[m][ct * 16 + l15][q4 * 8];
            const half8 wf1 = *(const half8*)&sWt[m][ct * 16 + l15][32 + q4 * 8];
            f32x4 d = {0.f, 0.f, 0.f, 0.f};
            d = __builtin_amdgcn_mfma_f32_16x16x32_f16(xf[0], wf0, d, 0, 0, 0);
            d = __builtin_amdgcn_mfma_f32_16x16x32_f16(xf[1], wf1, d, 0, 0, 0);
            #pragma unroll
            for (int i = 0; i < 4; ++i)
                O[(size_t)(trow + q4 * 4 + i) * 64 + ct * 16 + l15] = f2h(d[i]);
        }
    }
    #pragma unroll
    for (int mt = 0; mt < 4; ++mt) {              // V^T: D rows=c, cols=t
        const half8 wf0 = *(const half8*)&sWt[2][mt * 16 + l15][q4 * 8];
        const half8 wf1 = *(const half8*)&sWt[2][mt * 16 + l15][32 + q4 * 8];
        f32x4 d = {0.f, 0.f, 0.f, 0.f};
        d = __builtin_amdgcn_mfma_f32_16x16x32_f16(wf0, xf[0], d, 0, 0, 0);
        d = __builtin_amdgcn_mfma_f32_16x16x32_f16(wf1, xf[1], d, 0, 0, 0);
        #pragma unroll
        for (int i = 0; i < 4; ++i)
            Vt[(size_t)(b * 64 + mt * 16 + q4 * 4 + i) * SEQ + t0 + wvi * 16 + l15] = f2h(d[i]);
    }
}

// ---------------------------------------------------------------------------
// Kernel 2: per-wave retention tile (16 t-rows), barrier-free chunk loop.
// Grid 512, block 128 (2 waves; tile = blockIdx*2 + wave). Window: 17 chunks.
// S^T = mfma(K, Q): lane holds 4 consecutive s at fixed t -> packed b64 write to
// wave-private sS; read back b128 as PV A-frag (same-wave LDS is in-order).
// ---------------------------------------------------------------------------
__global__ __launch_bounds__(128, 1) void attn_kernel(
    const unsigned short* __restrict__ Qh, const unsigned short* __restrict__ Kh,
    const unsigned short* __restrict__ Vt,
    const float* __restrict__ gnw, const float* __restrict__ gnb,
    float* __restrict__ out)
{
    __shared__ unsigned short sS[2][16][88];
    __shared__ float sO[2][16][68];
    __shared__ float sGW[64], sGB[64];

    const int tid  = threadIdx.x;
    const int wvi  = tid >> 6;
    const int lane = tid & 63;
    const int l15  = lane & 15, q4 = lane >> 4;
    const int tile = blockIdx.x * 2 + wvi;        // 0..1023
    const int b    = tile >> 9;
    const int t0   = (tile & 511) << 4;

    if (tid < 64) { sGW[tid] = gnw[tid]; sGB[tid] = gnb[tid]; }
    __syncthreads();                              // only barrier in the kernel

    const unsigned short* Qp = Qh + (size_t)(b * SEQ + t0 + l15) * 64 + q4 * 8;
    const half8 qf0 = *(const half8*)Qp;
    const half8 qf1 = *(const half8*)(Qp + 32);

    float grs[4][4];                              // gamma^(trel - srel), chunk-invariant
    #pragma unroll
    for (int st = 0; st < 4; ++st) {
        #pragma unroll
        for (int i = 0; i < 4; ++i)
            grs[st][i] = exp2f((float)(l15 - (st * 16 + q4 * 4 + i)) * LOG2G);
    }

    f32x4 acc[4];
    #pragma unroll
    for (int ct = 0; ct < 4; ++ct) acc[ct] = (f32x4){0.f, 0.f, 0.f, 0.f};

    const int cs_hi = (t0 + 15) >> 6;
    const int cs_lo = (cs_hi >= 16) ? (cs_hi - 16) : 0;

    const unsigned short* Kbase = Kh + (size_t)b * SEQ * 64;
    const unsigned short* Vbase = Vt + (size_t)b * 64 * SEQ;

    half8 kA[4][2], vA[4][2], kB[4][2], vB[4][2];

    auto loadKV = [&](int cs, half8 (&kf)[4][2], half8 (&vf)[4][2]) {
        const int s0 = cs << 6;
        #pragma unroll
        for (int st = 0; st < 4; ++st) {
            const unsigned short* p = Kbase + (size_t)(s0 + st * 16 + l15) * 64 + q4 * 8;
            kf[st][0] = *(const half8*)p;
            kf[st][1] = *(const half8*)(p + 32);
        }
        #pragma unroll
        for (int ct = 0; ct < 4; ++ct) {
            const unsigned short* p = Vbase + (size_t)(ct * 16 + l15) * SEQ + s0 + q4 * 8;
            vf[ct][0] = *(const half8*)p;
            vf[ct][1] = *(const half8*)(p + 32);
        }
    };

    auto body = [&](half8 (&kc)[4][2], half8 (&vc)[4][2],
                    half8 (&kn)[4][2], half8 (&vn)[4][2], int cs) {
        const int s0 = cs << 6;
        f32x4 sv[4];
        #pragma unroll
        for (int st = 0; st < 4; ++st) {          // S^T: m=s (4 tiles), n=t
            f32x4 s = {0.f, 0.f, 0.f, 0.f};
            s = __builtin_amdgcn_mfma_f32_16x16x32_f16(kc[st][0], qf0, s, 0, 0, 0);
            s = __builtin_amdgcn_mfma_f32_16x16x32_f16(kc[st][1], qf1, s, 0, 0, 0);
            sv[st] = s;
        }
        if (cs < cs_hi) loadKV(cs + 1, kn, vn);   // prefetch next chunk into regs
        const float gbase = exp2f((float)(t0 - s0) * LOG2G);
        if (s0 + 63 <= t0) {                      // fully-causal chunk: no mask
            #pragma unroll
            for (int st = 0; st < 4; ++st) {
                const unsigned u0 = (unsigned)f2h(sv[st][0] * (gbase * grs[st][0]))
                                  | ((unsigned)f2h(sv[st][1] * (gbase * grs[st][1])) << 16);
                const unsigned u1 = (unsigned)f2h(sv[st][2] * (gbase * grs[st][2]))
                                  | ((unsigned)f2h(sv[st][3] * (gbase * grs[st][3])) << 16);
                unsigned int* p = (unsigned int*)&sS[wvi][l15][st * 16 + q4 * 4];
                p[0] = u0; p[1] = u1;
            }
        } else {                                  // diagonal chunks: per-element mask
            const int dbase = t0 + l15 - s0;
            #pragma unroll
            for (int st = 0; st < 4; ++st) {
                float w[4];
                #pragma unroll
                for (int i = 0; i < 4; ++i) {
                    const int srel = st * 16 + q4 * 4 + i;
                    w[i] = (dbase - srel >= 0) ? gbase * grs[st][i] : 0.f;
                }
                const unsigned u0 = (unsigned)f2h(sv[st][0] * w[0])
                                  | ((unsigned)f2h(sv[st][1] * w[1]) << 16);
                const unsigned u1 = (unsigned)f2h(sv[st][2] * w[2])
                                  | ((unsigned)f2h(sv[st][3] * w[3]) << 16);
                unsigned int* p = (unsigned int*)&sS[wvi][l15][st * 16 + q4 * 4];
                p[0] = u0; p[1] = u1;
            }
        }
        // A-frags from wave-private LDS (in-order within a wave; no barrier)
        const half8 af0 = *(const half8*)&sS[wvi][l15][q4 * 8];
        const half8 af1 = *(const half8*)&sS[wvi][l15][32 + q4 * 8];
        #pragma unroll
        for (int ct = 0; ct < 4; ++ct) {
            acc[ct] = __builtin_amdgcn_mfma_f32_16x16x32_f16(af0, vc[ct][0], acc[ct], 0, 0, 0);
            acc[ct] = __builtin_amdgcn_mfma_f32_16x16x32_f16(af1, vc[ct][1], acc[ct], 0, 0, 0);
        }
    };

    loadKV(cs_lo, kA, vA);
    int cs = cs_lo;
    while (true) {                                // 2x unroll: register ping-pong, no copies
        body(kA, vA, kB, vB, cs);
        if (++cs > cs_hi) break;
        body(kB, vB, kA, vA, cs);
        if (++cs > cs_hi) break;
    }

    // ---- epilogue: GroupNorm (8 groups of 8, biased var) + transposed store ----
    #pragma unroll
    for (int ct = 0; ct < 4; ++ct) {
        #pragma unroll
        for (int i = 0; i < 4; ++i)
            sO[wvi][q4 * 4 + i][ct * 16 + l15] = acc[ct][i];   // D: row=t, col=c
    }
    const int tt = lane >> 2, g2 = lane & 3;      // lane owns row tt, groups {2g2, 2g2+1}
    float x[16];
    #pragma unroll
    for (int j = 0; j < 4; ++j)
        *(f32x4*)&x[j * 4] = *(const f32x4*)&sO[wvi][tt][g2 * 16 + j * 4];
    #pragma unroll
    for (int gg = 0; gg < 2; ++gg) {
        float s = 0.f, ss = 0.f;
        #pragma unroll
        for (int j = 0; j < 8; ++j) { const float v = x[gg * 8 + j]; s += v; ss += v * v; }
        const float mu  = s * 0.125f;
        const float var = ss * 0.125f - mu * mu;
        const float rs  = rsqrtf(var + 1e-6f);
        #pragma unroll
        for (int j = 0; j < 8; ++j) {
            const int c = g2 * 16 + gg * 8 + j;
            x[gg * 8 + j] = (x[gg * 8 + j] - mu) * rs * sGW[c] + sGB[c];
        }
    }
    #pragma unroll
    for (int j = 0; j < 4; ++j)
        *(f32x4*)&sO[wvi][tt][g2 * 16 + j * 4] = *(f32x4*)&x[j * 4];
    #pragma unroll
    for (int k = 0; k < 16; ++k) {                // coalesced: 4 c-rows x 16 t (64B)
        const int c = k * 4 + q4;
        out[(size_t)(b * 64 + c) * SEQ + t0 + l15] = sO[wvi][l15][c];
    }
}

// ---------------------------------------------------------------------------
extern "C" void kernel_launch(void* const* d_in, const int* in_sizes, int n_in,
                              void* d_out, int out_size, void* d_ws, size_t ws_size,
                              hipStream_t stream)
{
    const float* Xin = (const float*)d_in[0];
    const float* Wq  = (const float*)d_in[1];
    const float* Wk  = (const float*)d_in[2];
    const float* Wv  = (const float*)d_in[3];
    const float* gnw = (const float*)d_in[4];
    const float* gnb = (const float*)d_in[5];

    const size_t NROW = (size_t)2 * SEQ;          // 16384
    unsigned short* Qh = (unsigned short*)d_ws;   // 2 MB each (fp16)
    unsigned short* Kh = Qh + NROW * CH;
    unsigned short* Vt = Kh + NROW * CH;

    qkv_kernel<<<dim3(256), dim3(256), 0, stream>>>(Xin, Wq, Wk, Wv, Qh, Kh, Vt);
    attn_kernel<<<dim3(512), dim3(128), 0, stream>>>(Qh, Kh, Vt, gnw, gnb, (float*)d_out);
}